// Round 6
// baseline (479.339 us; speedup 1.0000x reference)
//
#include <hip/hip_runtime.h>
#include <hip/hip_bf16.h>

typedef __hip_bfloat16 bf16;
typedef __attribute__((ext_vector_type(8))) short bf16x8;
typedef __attribute__((ext_vector_type(4))) float f32x4;

#define BB 8
#define SS 512
#define DD 512
#define NH 8
#define DHm 256
#define DFF 2048

__device__ __forceinline__ void gl_lds16(const void* g, void* l) {
  __builtin_amdgcn_global_load_lds((const __attribute__((address_space(1))) void*)g,
                                   (__attribute__((address_space(3))) void*)l, 16, 0, 0);
}

__device__ __forceinline__ bf16x8 cvt8(const float* p) {
  union { bf16x8 v; bf16 h[8]; } u;
  float4 f0 = *(const float4*)p, f1 = *(const float4*)(p + 4);
  u.h[0]=__float2bfloat16(f0.x); u.h[1]=__float2bfloat16(f0.y);
  u.h[2]=__float2bfloat16(f0.z); u.h[3]=__float2bfloat16(f0.w);
  u.h[4]=__float2bfloat16(f1.x); u.h[5]=__float2bfloat16(f1.y);
  u.h[6]=__float2bfloat16(f1.z); u.h[7]=__float2bfloat16(f1.w);
  return u.v;
}

// ================= bf16 MFMA GEMM, BK=64, swizzled LDS =================
// A (M,K) bf16 rm; B (N,K) bf16 rm. LDS row = 64 bf16 (128 B); the 8-element
// k-block kb is stored at kb ^ (row&7) (swizzled at the GLOBAL source so the
// wave-uniform global_load_lds dest stays lane-contiguous). Frag reads then
// hit banks 2-way max. 4 waves (2x2). SMODE:1 fp32,2 bf16,3 both.
// BIASM: 0 none, 1 per-col fp32 (bias + z*sBias), 2 scalar bias[0]+bias[1].
// EXTRA==1 (vnqn): z==0 also store E0=act(v)*hs[col]; z==1 also store E1 = C^T per 512-batch.
template<int BM, int BN, int SMODE, int BIASM, int ACT, int EXTRA>
__global__ __launch_bounds__(256)
void gemm2(const bf16* __restrict__ A, const bf16* __restrict__ B,
           const float* __restrict__ bias, float* __restrict__ Cf,
           bf16* __restrict__ Cb, int K, int lda, int ldb, int ldc,
           long long sA, long long sB, long long sC, long long sBias,
           const float* __restrict__ hs, bf16* __restrict__ E0, bf16* __restrict__ E1)
{
  __shared__ bf16 As[BM * 64];
  __shared__ bf16 Bs[BN * 64];
  const int t = threadIdx.x, lane = t & 63, wave = t >> 6;
  const int l15 = lane & 15, quad = lane >> 4;
  constexpr int WMT = BM / 32, WNT = BN / 32;
  const int wm = (wave & 1) * (BM / 2), wn = (wave >> 1) * (BN / 2);
  const int z = blockIdx.z;
  const int row0 = blockIdx.y * BM, col0 = blockIdx.x * BN;
  const bf16* Ab = A + (long long)z * sA + (long long)row0 * lda;
  const bf16* Bb = B + (long long)z * sB + (long long)col0 * ldb;
  // staging: 8 threads per 128B row; global k-block xor-swizzled by row&7
  const int srow = wave * 8 + (lane >> 3);             // row within a 32-row round
  const int skc  = (((lane & 7) ^ (lane >> 3)) << 3);  // swizzled k offset (elements)

  f32x4 acc[WMT][WNT] = {};

  for (int k0 = 0; k0 < K; k0 += 64) {
#pragma unroll
    for (int j = 0; j < BM / 32; j++)
      gl_lds16(Ab + (long long)(srow + j * 32) * lda + k0 + skc,
               (char*)As + j * 4096 + wave * 1024);
#pragma unroll
    for (int j = 0; j < BN / 32; j++)
      gl_lds16(Bb + (long long)(srow + j * 32) * ldb + k0 + skc,
               (char*)Bs + j * 4096 + wave * 1024);
    __syncthreads();
#pragma unroll
    for (int h = 0; h < 2; h++) {
      bf16x8 af[WMT], bfr[WNT];
#pragma unroll
      for (int i = 0; i < WMT; i++) {
        int m = wm + i * 16 + l15;
        af[i] = *(const bf16x8*)&As[m * 64 + (((h * 4 + quad) ^ (m & 7)) << 3)];
      }
#pragma unroll
      for (int j = 0; j < WNT; j++) {
        int n = wn + j * 16 + l15;
        bfr[j] = *(const bf16x8*)&Bs[n * 64 + (((h * 4 + quad) ^ (n & 7)) << 3)];
      }
#pragma unroll
      for (int i = 0; i < WMT; i++)
#pragma unroll
        for (int j = 0; j < WNT; j++)
          acc[i][j] = __builtin_amdgcn_mfma_f32_16x16x32_bf16(af[i], bfr[j], acc[i][j], 0, 0, 0);
    }
    __syncthreads();
  }

  float sb = 0.f;
  if (BIASM == 2) sb = bias[0] + bias[1];
#pragma unroll
  for (int i = 0; i < WMT; i++)
#pragma unroll
    for (int j = 0; j < WNT; j++) {
      int col = col0 + wn + j * 16 + l15;
      float bv = (BIASM == 1) ? bias[(long long)z * sBias + col] : sb;
      float hv = (EXTRA == 1) ? hs[col] : 0.f;
#pragma unroll
      for (int r = 0; r < 4; r++) {
        int row = row0 + wm + i * 16 + (quad << 2) + r;
        float v = acc[i][j][r] + bv;
        if (ACT == 1) v = fmaxf(v, 0.f);
        if (ACT == 2) v = 0.5f * v * (1.f + erff(v * 0.70710678118654752f));
        long long ci = (long long)z * sC + (long long)row * ldc + col;
        if (SMODE & 1) Cf[ci] = v;
        if (SMODE & 2) Cb[ci] = __float2bfloat16(v);
        if (EXTRA == 1) {
          if (z == 0) E0[(long long)row * ldc + col] = __float2bfloat16(v * hv);
          else {
            int bb = row >> 9, q = row & 511;
            E1[((long long)bb << 18) + (long long)col * 512 + q] = __float2bfloat16(v);
          }
        }
      }
    }
}

// ================= MFMA attention (both branches, one launch) =================
// grid (qt=8, h=8, z=16): b = z&7, branch = z>>3. QKV (2,4096,768) bf16.
__global__ __launch_bounds__(256, 2)
void attn_mfma(const bf16* __restrict__ QKV, const int* __restrict__ mask,
               const float* __restrict__ adjoin, const float* __restrict__ dist,
               float* __restrict__ awl, float* __restrict__ awg,
               bf16* __restrict__ ctx)
{
  const int qt = blockIdx.x, h = blockIdx.y;
  const int b = blockIdx.z & 7, br = blockIdx.z >> 3;
  const int t = threadIdx.x, lane = t & 63, wave = t >> 6;
  const int l15 = lane & 15, quad = lane >> 4;
  __shared__ bf16x8 Vt[64][32];

  const bf16* QKVb = QKV + (long long)br * 4096 * 768;
  {
    const bf16* Vb = QKVb + (long long)b * SS * 768 + 512 + h * 32;
    int dep = t & 31;
#pragma unroll
    for (int j8 = 0; j8 < 8; j8++) {
      int blk = (t >> 5) + (j8 << 3);
      union { bf16x8 v; bf16 hh[8]; } u;
#pragma unroll
      for (int i = 0; i < 8; i++)
        u.hh[i] = Vb[(long long)(blk * 8 + i) * 768 + dep];
      Vt[blk][dep] = u.v;
    }
  }

  const int q0 = qt * 64 + wave * 16;
  const bf16* Qb = QKVb + ((long long)(b * SS + q0)) * 768 + h * 32;
  bf16x8 qfrag = *(const bf16x8*)(Qb + (long long)l15 * 768 + quad * 8);
  __syncthreads();

  const float scale_inv = 0.17677669529663688f; // 1/sqrt(32)
  const bf16* Kb = QKVb + (long long)b * SS * 768 + 256 + h * 32;
  const float* Eb = (br == 0 ? adjoin : dist) + ((long long)b * SS + q0) * SS;
  float sreg[32][4];
  float rmax[4] = {-1e30f, -1e30f, -1e30f, -1e30f};
#pragma unroll
  for (int kc = 0; kc < 32; kc++) {
    int kpos = kc * 16 + l15;
    bf16x8 kfrag = *(const bf16x8*)(Kb + (long long)kpos * 768 + quad * 8);
    f32x4 a = __builtin_amdgcn_mfma_f32_16x16x32_bf16(qfrag, kfrag, f32x4{0.f,0.f,0.f,0.f}, 0, 0, 0);
    float mval = (float)mask[b * SS + kpos] * -1e9f;
#pragma unroll
    for (int r = 0; r < 4; r++) {
      float s = a[r];
      float ev = Eb[(long long)(quad * 4 + r) * SS + kpos];
      if (br == 0) {
        s = s * scale_inv + mval + ev;
      } else {
        float resc = 3.7182818284590452f / (1.f + __expf(1.f - ev));
        s = fmaxf(s, 0.f) * resc * scale_inv + mval;
      }
      sreg[kc][r] = s;
      rmax[r] = fmaxf(rmax[r], s);
    }
  }
#pragma unroll
  for (int r = 0; r < 4; r++) {
    float v = rmax[r];
    v = fmaxf(v, __shfl_xor(v, 1, 16));
    v = fmaxf(v, __shfl_xor(v, 2, 16));
    v = fmaxf(v, __shfl_xor(v, 4, 16));
    v = fmaxf(v, __shfl_xor(v, 8, 16));
    rmax[r] = v;
  }
  float rsum[4] = {0.f, 0.f, 0.f, 0.f};
#pragma unroll
  for (int kc = 0; kc < 32; kc++)
#pragma unroll
    for (int r = 0; r < 4; r++) {
      float e = __expf(sreg[kc][r] - rmax[r]);
      sreg[kc][r] = e;
      rsum[r] += e;
    }
#pragma unroll
  for (int r = 0; r < 4; r++) {
    float v = rsum[r];
    v += __shfl_xor(v, 1, 16);
    v += __shfl_xor(v, 2, 16);
    v += __shfl_xor(v, 4, 16);
    v += __shfl_xor(v, 8, 16);
    rsum[r] = 1.f / v;
  }
  float* awp = (br == 0 ? awl : awg) + (((long long)(b * NH + h) * SS + q0)) * SS;
#pragma unroll
  for (int kc = 0; kc < 32; kc++)
#pragma unroll
    for (int r = 0; r < 4; r++)
      awp[(long long)(quad * 4 + r) * SS + kc * 16 + l15] = sreg[kc][r] * rsum[r];

  asm volatile("s_waitcnt vmcnt(0)" ::: "memory");

  f32x4 oacc[2] = {};
#pragma unroll
  for (int kc2 = 0; kc2 < 16; kc2++) {
    bf16x8 afr = cvt8(awp + (long long)l15 * SS + kc2 * 32 + quad * 8);
#pragma unroll
    for (int n = 0; n < 2; n++) {
      bf16x8 bfr = Vt[kc2 * 4 + quad][n * 16 + l15];
      oacc[n] = __builtin_amdgcn_mfma_f32_16x16x32_bf16(afr, bfr, oacc[n], 0, 0, 0);
    }
  }
  bf16* ctxb = ctx + (long long)br * 4096 * DHm;
#pragma unroll
  for (int n = 0; n < 2; n++)
#pragma unroll
    for (int r = 0; r < 4; r++) {
      int q = q0 + quad * 4 + r;
      ctxb[(long long)(b * SS + q) * DHm + h * 32 + n * 16 + l15] = __float2bfloat16(oacc[n][r]);
    }
}

// ================= pack_all =================
__device__ __forceinline__ void tr_tile(const float* __restrict__ src, bf16* __restrict__ dst,
                                        int K, int N, int tile) {
  __shared__ float tl[32][33];
  int tilesN = N >> 5;
  int tk = tile / tilesN, tn = tile % tilesN;
  int c = threadIdx.x & 31, r0 = threadIdx.x >> 5;
#pragma unroll
  for (int i = 0; i < 4; i++) {
    int r = r0 + i * 8;
    tl[r][c] = src[(long long)(tk * 32 + r) * N + tn * 32 + c];
  }
  __syncthreads();
#pragma unroll
  for (int i = 0; i < 4; i++) {
    int r = r0 + i * 8;
    dst[(long long)(tn * 32 + r) * K + tk * 32 + c] = __float2bfloat16(tl[c][r]);
  }
}

__global__ __launch_bounds__(256)
void pack_all(const float* wq1, const float* wk1, const float* wv1,
              const float* wq2, const float* wk2, const float* wv2,
              const float* wo1, const float* wo2,
              const float* vnet_w, const float* qnet_w,
              const float* ffn_w1, const float* ffn_w2,
              const float* bq1, const float* bk1, const float* bv1,
              const float* bq2, const float* bk2, const float* bv2,
              const float* bo1, const float* bo2,
              const float* vnet_b, const float* qnet_b, const float* h_mat,
              const float* x,
              bf16* WB1, bf16* WB2, bf16* woT1, bf16* woT2,
              bf16* vnetT, bf16* qnetT, bf16* f1T, bf16* f2T,
              float* BB1v, float* BB2v, float* BO2, float* BVQ, float* HS,
              bf16* xb)
{
  int blk = blockIdx.x;
  int t = threadIdx.x;
  if (blk < 64)        { tr_tile(wq1, WB1,            256, 256, blk); return; }
  if (blk < 128)       { tr_tile(wk1, WB1 + 256*256,  256, 256, blk-64); return; }
  if (blk < 192)       { tr_tile(wv1, WB1 + 512*256,  256, 256, blk-128); return; }
  if (blk < 256)       { tr_tile(wq2, WB2,            256, 256, blk-192); return; }
  if (blk < 320)       { tr_tile(wk2, WB2 + 256*256,  256, 256, blk-256); return; }
  if (blk < 384)       { tr_tile(wv2, WB2 + 512*256,  256, 256, blk-320); return; }
  if (blk < 448)       { tr_tile(wo1, woT1,           256, 256, blk-384); return; }
  if (blk < 512)       { tr_tile(wo2, woT2,           256, 256, blk-448); return; }
  if (blk < 640)       { tr_tile(vnet_w, vnetT,       256, 512, blk-512); return; }
  if (blk < 768)       { tr_tile(qnet_w, qnetT,       256, 512, blk-640); return; }
  if (blk < 1792)      { tr_tile(ffn_w1, f1T,         512, 2048, blk-768); return; }
  if (blk < 2816)      { tr_tile(ffn_w2, f2T,         2048, 512, blk-1792); return; }
  if (blk < 3840) {
    long long i0 = (long long)(blk - 2816) * 2048 + t * 8;
    *(bf16x8*)(xb + i0) = cvt8(x + i0);
    return;
  }
  int i = blk - 3840;
  if (i < 6) {
    const float* src = i==0?bq1 : i==1?bk1 : i==2?bv1 : i==3?bq2 : i==4?bk2 : bv2;
    float* dst = (i < 3 ? BB1v : BB2v) + (i % 3) * 256;
    dst[t] = src[t];
  } else if (i < 8)  { BO2[(i-6)*256 + t] = (i==6 ? bo1 : bo2)[t]; }
  else if (i < 10)   { BVQ[(i-8)*256 + t] = vnet_b[(i-8)*256 + t]; }
  else if (i < 12)   { BVQ[512 + (i-10)*256 + t] = qnet_b[(i-10)*256 + t]; }
  else               { int c = (i-12)*256 + t; HS[c] = h_mat[c] + h_mat[512 + c]; }
}

// ---------------- BN(eval) + gate + residual + LN1 (dual-store) ----------------
__global__ __launch_bounds__(256)
void bn_gate_ln1_kernel(const float* __restrict__ x, const bf16* __restrict__ vbuf,
                        const bf16* __restrict__ T, const bf16* __restrict__ xlg,
                        const float* __restrict__ bng, const float* __restrict__ bnb,
                        const float* __restrict__ bnm, const float* __restrict__ bnv,
                        const float* __restrict__ lng, const float* __restrict__ lnb,
                        float* __restrict__ out1, bf16* __restrict__ out1b)
{
  const int row = blockIdx.x;
  const int t = threadIdx.x;
  __shared__ float red[256];
  float val[2];
#pragma unroll
  for (int i = 0; i < 2; i++) {
    int c = t + i * 256;
    long long idx = (long long)row * DD + c;
    float lg = __bfloat162float(vbuf[idx]) * __bfloat162float(T[idx]);
    float bn = (lg - bnm[c]) / sqrtf(bnv[c] + 1e-3f) * bng[c] + bnb[c];
    // gate: c<256 -> XL, else XG; XLG layout (2,4096,256)
    long long gidx = (long long)(c >> 8) * 4096 * DHm + (long long)row * DHm + (c & 255);
    float gate = __bfloat162float(xlg[gidx]);
    val[i] = x[idx] + bn * gate;
  }
  red[t] = val[0] + val[1];
  __syncthreads();
  for (int o = 128; o > 0; o >>= 1) { if (t < o) red[t] += red[t + o]; __syncthreads(); }
  float mu = red[0] * (1.f / 512.f);
  __syncthreads();
  float d0 = val[0] - mu, d1 = val[1] - mu;
  red[t] = d0 * d0 + d1 * d1;
  __syncthreads();
  for (int o = 128; o > 0; o >>= 1) { if (t < o) red[t] += red[t + o]; __syncthreads(); }
  float inv = 1.f / sqrtf(red[0] * (1.f / 512.f) + 1e-6f);
  float o0 = d0 * inv * lng[t] + lnb[t];
  float o1 = d1 * inv * lng[t + 256] + lnb[t + 256];
  out1[(long long)row * DD + t] = o0;
  out1[(long long)row * DD + t + 256] = o1;
  out1b[(long long)row * DD + t] = __float2bfloat16(o0);
  out1b[(long long)row * DD + t + 256] = __float2bfloat16(o1);
}

// ---------------- residual + LN2 -> out ----------------
__global__ __launch_bounds__(256)
void ln2_kernel(const float* __restrict__ a, const bf16* __restrict__ b2,
                const float* __restrict__ g, const float* __restrict__ bta,
                float* __restrict__ out)
{
  const int row = blockIdx.x;
  const int t = threadIdx.x;
  __shared__ float red[256];
  float v0 = a[(long long)row * DD + t]       + __bfloat162float(b2[(long long)row * DD + t]);
  float v1 = a[(long long)row * DD + t + 256] + __bfloat162float(b2[(long long)row * DD + t + 256]);
  red[t] = v0 + v1;
  __syncthreads();
  for (int o = 128; o > 0; o >>= 1) { if (t < o) red[t] += red[t + o]; __syncthreads(); }
  float mu = red[0] * (1.f / 512.f);
  __syncthreads();
  float d0 = v0 - mu, d1 = v1 - mu;
  red[t] = d0 * d0 + d1 * d1;
  __syncthreads();
  for (int o = 128; o > 0; o >>= 1) { if (t < o) red[t] += red[t + o]; __syncthreads(); }
  float inv = 1.f / sqrtf(red[0] * (1.f / 512.f) + 1e-6f);
  out[(long long)row * DD + t]       = d0 * inv * g[t]       + bta[t];
  out[(long long)row * DD + t + 256] = d1 * inv * g[t + 256] + bta[t + 256];
}

extern "C" void kernel_launch(void* const* d_in, const int* in_sizes, int n_in,
                              void* d_out, int out_size, void* d_ws, size_t ws_size,
                              hipStream_t stream) {
  const float* x      = (const float*)d_in[0];
  const float* adjoin = (const float*)d_in[1];
  const float* dist   = (const float*)d_in[2];
  const float* wq1=(const float*)d_in[3],  *bq1=(const float*)d_in[4];
  const float* wk1=(const float*)d_in[5],  *bk1=(const float*)d_in[6];
  const float* wv1=(const float*)d_in[7],  *bv1=(const float*)d_in[8];
  const float* wo1=(const float*)d_in[9],  *bo1=(const float*)d_in[10];
  const float* wq2=(const float*)d_in[11], *bq2=(const float*)d_in[12];
  const float* wk2=(const float*)d_in[13], *bk2=(const float*)d_in[14];
  const float* wv2=(const float*)d_in[15], *bv2=(const float*)d_in[16];
  const float* wo2=(const float*)d_in[17], *bo2=(const float*)d_in[18];
  const float* vnet_w=(const float*)d_in[19], *vnet_b=(const float*)d_in[20];
  const float* qnet_w=(const float*)d_in[21], *qnet_b=(const float*)d_in[22];
  const float* h_mat=(const float*)d_in[23], *h_bias=(const float*)d_in[24];
  const float* bn_g=(const float*)d_in[25], *bn_b=(const float*)d_in[26];
  const float* bn_m=(const float*)d_in[27], *bn_v=(const float*)d_in[28];
  const float* ln1_g=(const float*)d_in[29], *ln1_b=(const float*)d_in[30];
  const float* ln2_g=(const float*)d_in[31], *ln2_b=(const float*)d_in[32];
  const float* ffn_w1=(const float*)d_in[33], *ffn_b1=(const float*)d_in[34];
  const float* ffn_w2=(const float*)d_in[35], *ffn_b2=(const float*)d_in[36];
  const int* mask = (const int*)d_in[37];

  char* base = (char*)d_ws;
  size_t off = 0;
  auto alloc = [&](size_t bytes) { char* p = base + off; off += (bytes + 255) & ~(size_t)255; return p; };
  bf16*  xb    = (bf16*) alloc(4096LL*512*2);
  bf16*  WB1   = (bf16*) alloc(768*256*2);     // contiguous with WB2
  bf16*  WB2   = (bf16*) alloc(768*256*2);
  float* BB1v  = (float*)alloc(768*4);         // contiguous with BB2v
  float* BB2v  = (float*)alloc(768*4);
  bf16*  woT1  = (bf16*) alloc(256*256*2);     // contiguous with woT2
  bf16*  woT2  = (bf16*) alloc(256*256*2);
  bf16*  vnetT = (bf16*) alloc(512*256*2);     // contiguous with qnetT
  bf16*  qnetT = (bf16*) alloc(512*256*2);
  bf16*  f1T   = (bf16*) alloc(2048*512*2);
  bf16*  f2T   = (bf16*) alloc(512*2048*2);
  float* BO2   = (float*)alloc(512*4);
  float* BVQ   = (float*)alloc(1024*4);
  float* HS    = (float*)alloc(512*4);
  bf16*  QKV   = (bf16*) alloc(2LL*4096*768*2);
  bf16*  CTX   = (bf16*) alloc(2LL*4096*256*2);
  bf16*  XLG   = (bf16*) alloc(2LL*4096*256*2);
  bf16*  Vn    = (bf16*) alloc(4096LL*512*2);  // contiguous with Qn
  bf16*  Qn    = (bf16*) alloc(4096LL*512*2);
  bf16*  QnT   = (bf16*) alloc(4096LL*512*2);
  bf16*  VH    = (bf16*) alloc(4096LL*512*2);
  bf16*  G     = (bf16*) alloc(8LL*512*512*2);
  bf16*  T     = (bf16*) alloc(4096LL*512*2);
  float* OUT1  = (float*)alloc(4096LL*512*4);
  bf16*  OUT1b = (bf16*) alloc(4096LL*512*2);
  bf16*  H     = (bf16*) alloc(4096LL*2048*2);
  bf16*  FFNO  = (bf16*) alloc(4096LL*512*2);

  float* out2 = (float*)d_out;
  float* awl  = out2 + 2097152LL;
  float* awg  = awl + 16777216LL;

  const int MR = BB * SS; // 4096
  const long long GST = (long long)SS * SS;

  // 1. pack
  pack_all<<<dim3(3854), 256, 0, stream>>>(
      wq1, wk1, wv1, wq2, wk2, wv2, wo1, wo2, vnet_w, qnet_w, ffn_w1, ffn_w2,
      bq1, bk1, bv1, bq2, bk2, bv2, bo1, bo2, vnet_b, qnet_b, h_mat, x,
      WB1, WB2, woT1, woT2, vnetT, qnetT, f1T, f2T, BB1v, BB2v, BO2, BVQ, HS, xb);

  // 2. QKV both branches (z=2), 128x64 tiles -> grid 12*32*2 = 768 blocks
  gemm2<128,64,2,1,0,0><<<dim3(768/64, MR/128, 2), 256, 0, stream>>>(
      xb, WB1, BB1v, nullptr, QKV, 256, 512, 256, 768,
      256, 768*256, 4096LL*768, 768, nullptr, nullptr, nullptr);

  // 3. attention, both branches (z = branch*8 + b)
  attn_mfma<<<dim3(8, NH, 16), 256, 0, stream>>>(QKV, mask, adjoin, dist, awl, awg, CTX);

  // 4. output projections (z=2)
  gemm2<64,64,2,1,0,0><<<dim3(4, 64, 2), 256, 0, stream>>>(
      CTX, woT1, BO2, nullptr, XLG, 256, 256, 256, 256,
      4096LL*256, 256*256, 4096LL*256, 256, nullptr, nullptr, nullptr);

  // 5. vnet/qnet (z=2) + fused vh (z=0) and Qn transpose (z=1)
  gemm2<64,64,2,1,1,1><<<dim3(8, 64, 2), 256, 0, stream>>>(
      XLG, vnetT, BVQ, nullptr, Vn, 256, 256, 256, 512,
      4096LL*256, 512*256, 4096LL*512, 512, HS, VH, QnT);

  // 6. G[b] = VH[b] @ Qn[b]^T + (hb0+hb1)
  gemm2<64,64,2,2,0,0><<<dim3(8, 8, 8), 256, 0, stream>>>(
      VH, Qn, h_bias, nullptr, G, 512, 512, 512, 512,
      GST, GST, GST, 0, nullptr, nullptr, nullptr);

  // 7. T[b] = G[b] @ Qn[b]  (B = QnT: (k,q) rows contiguous in q)
  gemm2<64,64,2,0,0,0><<<dim3(8, 8, 8), 256, 0, stream>>>(
      G, QnT, nullptr, nullptr, T, 512, 512, 512, 512,
      GST, GST, GST, 0, nullptr, nullptr, nullptr);

  // 8. BN + gate + residual + LN1
  bn_gate_ln1_kernel<<<dim3(MR), 256, 0, stream>>>(
      x, Vn, T, XLG, bn_g, bn_b, bn_m, bn_v, ln1_g, ln1_b, OUT1, OUT1b);

  // 9. FFN1 (gelu)
  gemm2<128,128,2,1,2,0><<<dim3(16, 32, 1), 256, 0, stream>>>(
      OUT1b, f1T, ffn_b1, nullptr, H, 512, 512, 512, 2048,
      0, 0, 0, 0, nullptr, nullptr, nullptr);

  // 10. FFN2
  gemm2<64,64,2,1,0,0><<<dim3(8, 64, 1), 256, 0, stream>>>(
      H, f2T, ffn_b2, nullptr, FFNO, 2048, 2048, 2048, 512,
      0, 0, 0, 0, nullptr, nullptr, nullptr);

  // 11. residual + LN2 -> out
  ln2_kernel<<<dim3(MR), 256, 0, stream>>>(OUT1, FFNO, ln2_g, ln2_b, out2);
}